// Round 4
// baseline (311.927 us; speedup 1.0000x reference)
//
#include <hip/hip_runtime.h>

// Two-pass 3x3 VALID conv:
//  pass 1: pack x fp32 [16][2048][2048] -> xt bf16 [h][w][16ci] in d_ws,
//          ci-half 16B chunks swapped when (w&4)  (pre-swizzle for LDS reads)
//  pass 2: implicit-GEMM conv; per 32x32 tile stage 34x34x16ci via
//          global_load_lds(16B), 5x mfma_16x16x32_bf16 per 16x16 out.
//          512-thread blocks for 32 waves/CU occupancy.

#define HIN   2048
#define WIN   2048
#define HOUT  2046
#define WOUT  2046
#define PLANE_IN  (HIN * WIN)
#define PLANE_OUT (HOUT * WOUT)
#define TR 34
#define TC 34
#define NCHUNK (TR * TC * 2)   // 2312 16B-chunks per tile

typedef __attribute__((ext_vector_type(8))) short bf16x8;
typedef __attribute__((ext_vector_type(4))) float f32x4;
typedef __attribute__((ext_vector_type(4))) unsigned u32x4;
typedef f32x4 __attribute__((aligned(4))) f32x4_u;

static __device__ __forceinline__ short f2bf(float f) {
    unsigned u = __float_as_uint(f);
    return (short)((u + 0x7FFFu + ((u >> 16) & 1u)) >> 16);   // RNE
}
// scalar RNE pack of two fp32 -> packed bf16x2 (no inline asm: m240)
static __device__ __forceinline__ unsigned pk2(float lo, float hi) {
    unsigned a = __float_as_uint(lo);
    unsigned b = __float_as_uint(hi);
    a = (a + 0x7FFFu + ((a >> 16) & 1u)) >> 16;
    b = (b + 0x7FFFu + ((b >> 16) & 1u)) & 0xFFFF0000u;
    return a | b;
}

// ---------------- pass 1: pack/transpose/convert ----------------
__global__ __launch_bounds__(256, 4)
void pack_bf16(const float* __restrict__ x, unsigned* __restrict__ xt) {
    int id = blockIdx.x * 256 + threadIdx.x;   // w-quad id: 2048 rows x 512 quads
    int h  = id >> 9;
    int w0 = (id & 511) << 2;
    const float* gp = x + h * WIN + w0;
    float v[16][4];
    #pragma unroll
    for (int ci = 0; ci < 16; ++ci) {
        float4 f = *(const float4*)(gp + ci * PLANE_IN);
        v[ci][0] = f.x; v[ci][1] = f.y; v[ci][2] = f.z; v[ci][3] = f.w;
    }
    int sw = (w0 & 4) ? 4 : 0;                 // chunk swap keyed on w&4
    unsigned* op = xt + (h * WIN + w0) * 8;    // 8 u32 per position
    #pragma unroll
    for (int j = 0; j < 4; ++j) {
        u32x4 lo, hi;
        #pragma unroll
        for (int p = 0; p < 4; ++p) lo[p] = pk2(v[2 * p][j],     v[2 * p + 1][j]);
        #pragma unroll
        for (int p = 0; p < 4; ++p) hi[p] = pk2(v[2 * p + 8][j], v[2 * p + 9][j]);
        unsigned* pp = op + j * 8;
        *(u32x4*)(pp + sw)       = lo;         // ci0-7
        *(u32x4*)(pp + (4 - sw)) = hi;         // ci8-15
    }
}

// ---------------- pass 2: MFMA conv (512 threads / 8 waves) ----------------
__global__ __launch_bounds__(512, 8)
void conv3x3_mfma2(const unsigned* __restrict__ xt,
                   const float* __restrict__ k,
                   float* __restrict__ out) {
    __shared__ unsigned lds[NCHUNK * 4];   // 36992 B, linear [row][col][ci-chunk]

    const int tid  = threadIdx.x;
    const int lane = tid & 63;
    const int wv   = tid >> 6;             // 0..7
    const int m    = lane & 15;
    const int g    = lane >> 4;

    int bid = blockIdx.x;
    int swz = (bid & 7) * 512 + (bid >> 3);    // XCD-chunked (4096 % 8 == 0)
    int h0 = (swz >> 6) * 32; if (h0 > HOUT - 32) h0 = HOUT - 32;  // 2014
    int w0 = (swz & 63) * 32;

    // ---- stage tile: 2312 chunks of 16B, linear LDS dest, per-lane gsrc ----
    {
        int base = wv * 64;
        #pragma unroll
        for (int pass = 0; pass < 4; ++pass) {
            int c   = pass * 512 + tid;
            int row = (c * 964) >> 16;          // c/68, exact for c<2312
            int sub = c - row * 68;
            int w   = w0 + (sub >> 1); if (w > WIN - 1) w = WIN - 1;
            const unsigned* src = xt + ((h0 + row) * WIN + w) * 8 + (sub & 1) * 4;
            __builtin_amdgcn_global_load_lds(
                (const __attribute__((address_space(1))) unsigned*)src,
                (__attribute__((address_space(3))) unsigned*)&lds[(pass * 512 + base) * 4],
                16, 0, 0);
        }
        if (tid < 264) {                        // tail: chunks 2048+tid .. 2311
            int c   = 2048 + tid;
            int row = (c * 964) >> 16;
            int sub = c - row * 68;
            int w   = w0 + (sub >> 1); if (w > WIN - 1) w = WIN - 1;
            const unsigned* src = xt + ((h0 + row) * WIN + w) * 8 + (sub & 1) * 4;
            __builtin_amdgcn_global_load_lds(
                (const __attribute__((address_space(1))) unsigned*)src,
                (__attribute__((address_space(3))) unsigned*)&lds[(2048 + base) * 4],
                16, 0, 0);
        }
    }

    // ---- weight B-fragments (overlap staging latency): W[co=m][k=32i+8g+j] ----
    bf16x8 wf[5];
    #pragma unroll
    for (int i = 0; i < 5; ++i) {
        #pragma unroll
        for (int j = 0; j < 8; ++j) {
            int kk  = 32 * i + 8 * g + j;
            int tap = kk >> 4;
            int ci  = kk & 15;
            short v = 0;
            if (tap < 9) v = f2bf(k[(m * 16 + ci) * 9 + tap]);
            wf[i][j] = v;
        }
    }

    // ---- per-lane A-fragment LDS byte offsets ----
    int off[5];
    #pragma unroll
    for (int i = 0; i < 5; ++i) {
        int tap = 2 * i + (g >> 1);
        if (tap > 8) tap = 8;                   // dead K (weights are 0)
        int kh = tap / 3;
        int kw = tap - kh * 3;
        int col = m + kw;                       // wl enters via tile base (bit4-safe)
        int o = (kh * TC + col) * 32 + (g & 1) * 16;
        off[i] = o ^ ((col & 4) << 2);          // matches xt pre-swizzle
    }

    __syncthreads();

    const char* ldsb = (const char*)lds;

    #pragma unroll
    for (int hl4 = 0; hl4 < 4; ++hl4) {
        int hl = wv * 4 + hl4;                  // h always < HOUT (h0 <= 2014)
        int h  = h0 + hl;
        #pragma unroll
        for (int nh = 0; nh < 2; ++nh) {
            int wl = nh * 16;
            int tb = (hl * TC + wl) * 32;
            f32x4 acc = {0.f, 0.f, 0.f, 0.f};
            #pragma unroll
            for (int i = 0; i < 5; ++i) {
                bf16x8 a = *(const bf16x8*)(ldsb + (tb + off[i]));
                acc = __builtin_amdgcn_mfma_f32_16x16x32_bf16(a, wf[i], acc, 0, 0, 0);
            }
            // D: row = g*4+r = spatial, col = m = co  ->  float4 store
            int w = w0 + wl + g * 4;
            float* op = out + m * PLANE_OUT + h * WOUT + w;
            if (w + 3 < WOUT) {
                *(f32x4_u*)op = acc;
            } else {
                #pragma unroll
                for (int r = 0; r < 4; ++r)
                    if (w + r < WOUT) op[r] = acc[r];
            }
        }
    }
}

// ---------------- fallback (single-pass), used if ws too small ----------------
__global__ __launch_bounds__(256, 4)
void conv3x3_mfma(const float* __restrict__ x,
                  const float* __restrict__ k,
                  float* __restrict__ out) {
    __shared__ short lds[TR * TC * 16];
    const int tid  = threadIdx.x;
    const int lane = tid & 63;
    const int wv   = tid >> 6;
    const int m    = lane & 15;
    const int g    = lane >> 4;
    int bid = blockIdx.x;
    int swz = (bid & 7) * 512 + (bid >> 3);
    int h0 = (swz >> 6) * 32;
    int w0 = (swz & 63) * 32;
    for (int p = tid; p < TR * TC; p += 256) {
        int r = p / TC, c = p - r * TC;
        int hh = h0 + r; if (hh > HIN - 1) hh = HIN - 1;
        int ww = w0 + c; if (ww > WIN - 1) ww = WIN - 1;
        const float* gp = x + hh * WIN + ww;
        short t[16];
        #pragma unroll
        for (int ci = 0; ci < 16; ++ci) t[ci] = f2bf(gp[ci * PLANE_IN]);
        bf16x8 lo, hi;
        #pragma unroll
        for (int j = 0; j < 8; ++j) { lo[j] = t[j]; hi[j] = t[8 + j]; }
        int sw = (c >> 2) & 1;
        bf16x8* dst = (bf16x8*)&lds[p * 16];
        dst[sw] = lo; dst[1 - sw] = hi;
    }
    bf16x8 wf[5];
    #pragma unroll
    for (int i = 0; i < 5; ++i)
        #pragma unroll
        for (int j = 0; j < 8; ++j) {
            int kk = 32 * i + 8 * g + j;
            int tap = kk >> 4, ci = kk & 15;
            short v = 0;
            if (tap < 9) v = f2bf(k[(m * 16 + ci) * 9 + tap]);
            wf[i][j] = v;
        }
    int off[5];
    #pragma unroll
    for (int i = 0; i < 5; ++i) {
        int tap = 2 * i + (g >> 1);
        if (tap > 8) tap = 8;
        int kh = tap / 3, kw = tap - kh * 3;
        int col = m + kw;
        int o = (kh * TC + col) * 32 + (g & 1) * 16;
        off[i] = o ^ ((col & 4) << 2);
    }
    __syncthreads();
    const char* ldsb = (const char*)lds;
    const int coBase = g * 4;
    for (int hl8 = 0; hl8 < 8; ++hl8) {
        int hl = wv * 8 + hl8;
        int h = h0 + hl;
        bool hok = (h < HOUT);
        #pragma unroll
        for (int nh = 0; nh < 2; ++nh) {
            int wl = nh * 16;
            int tb = (hl * TC + wl) * 32;
            f32x4 acc = {0.f, 0.f, 0.f, 0.f};
            #pragma unroll
            for (int i = 0; i < 5; ++i) {
                bf16x8 b = *(const bf16x8*)(ldsb + (tb + off[i]));
                acc = __builtin_amdgcn_mfma_f32_16x16x32_bf16(wf[i], b, acc, 0, 0, 0);
            }
            int w = w0 + wl + m;
            if (hok && w < WOUT) {
                float* op = out + h * WOUT + w;
                #pragma unroll
                for (int r = 0; r < 4; ++r)
                    op[(coBase + r) * PLANE_OUT] = acc[r];
            }
        }
    }
}

extern "C" void kernel_launch(void* const* d_in, const int* in_sizes, int n_in,
                              void* d_out, int out_size, void* d_ws, size_t ws_size,
                              hipStream_t stream) {
    const float* x = (const float*)d_in[0];
    const float* k = (const float*)d_in[1];
    float* out = (float*)d_out;
    const size_t need = (size_t)HIN * WIN * 16 * 2;   // 128 MiB xt
    if (ws_size >= need) {
        unsigned* xt = (unsigned*)d_ws;
        pack_bf16<<<dim3(4096), dim3(256), 0, stream>>>(x, xt);
        conv3x3_mfma2<<<dim3(4096), dim3(512), 0, stream>>>(xt, k, out);
    } else {
        conv3x3_mfma<<<dim3(4096), dim3(256), 0, stream>>>(x, k, out);
    }
}

// Round 5
// 220.772 us; speedup vs baseline: 1.4129x; 1.4129x over previous
//
#include <hip/hip_runtime.h>

// Two-pass 3x3 VALID conv:
//  pass 1: pack x fp32 [16][2048][2048] -> xt bf16 [h][w][16ci] in d_ws
//          (ci-half 16B chunks swapped when (w&4) — pre-swizzle for LDS reads);
//          block 0 also precomputes per-lane MFMA weight fragments -> d_ws.
//  pass 2: implicit-GEMM conv; per 32x32 tile stage 34x34x16ci via
//          global_load_lds(16B), 5x mfma_16x16x32_bf16 per 16x16 out.
//          Weight fragments loaded with 5 coalesced 16B loads (no per-thread
//          gather/convert — that was 84M scalar loads across the launch).

#define HIN   2048
#define WIN   2048
#define HOUT  2046
#define WOUT  2046
#define PLANE_IN  (HIN * WIN)
#define PLANE_OUT (HOUT * WOUT)
#define TR 34
#define TC 34
#define NCHUNK (TR * TC * 2)           // 2312 16B-chunks per tile
#define XT_U32 ((size_t)HIN * WIN * 8) // xt size in u32
#define WF_U32 (5 * 64 * 4)            // weight-frag buffer in u32 (5 KiB)

typedef __attribute__((ext_vector_type(8))) short bf16x8;
typedef __attribute__((ext_vector_type(4))) float f32x4;
typedef __attribute__((ext_vector_type(4))) unsigned u32x4;
typedef f32x4 __attribute__((aligned(4))) f32x4_u;

static __device__ __forceinline__ short f2bf(float f) {
    unsigned u = __float_as_uint(f);
    return (short)((u + 0x7FFFu + ((u >> 16) & 1u)) >> 16);   // RNE
}
// scalar RNE pack of two fp32 -> packed bf16x2
static __device__ __forceinline__ unsigned pk2(float lo, float hi) {
    unsigned a = __float_as_uint(lo);
    unsigned b = __float_as_uint(hi);
    a = (a + 0x7FFFu + ((a >> 16) & 1u)) >> 16;
    b = (b + 0x7FFFu + ((b >> 16) & 1u)) & 0xFFFF0000u;
    return a | b;
}

// ---------------- pass 1: pack/transpose/convert (+ weight fragments) --------
__global__ __launch_bounds__(256, 4)
void pack_bf16(const float* __restrict__ x, const float* __restrict__ k,
               unsigned* __restrict__ xt, unsigned* __restrict__ wfbuf) {
    // block 0, wave 0: precompute per-lane weight fragments (once, trivial)
    if (blockIdx.x == 0 && threadIdx.x < 64) {
        int lane = threadIdx.x;
        int m = lane & 15, g = lane >> 4;
        #pragma unroll
        for (int i = 0; i < 5; ++i) {
            u32x4 q;
            #pragma unroll
            for (int jj = 0; jj < 4; ++jj) {
                unsigned r = 0;
                #pragma unroll
                for (int e = 0; e < 2; ++e) {
                    int kk  = 32 * i + 8 * g + 2 * jj + e;
                    int tap = kk >> 4;
                    int ci  = kk & 15;
                    unsigned v = 0;
                    if (tap < 9) v = (unsigned short)f2bf(k[(m * 16 + ci) * 9 + tap]);
                    r |= v << (16 * e);
                }
                q[jj] = r;
            }
            *(u32x4*)(wfbuf + (i * 64 + lane) * 4) = q;
        }
    }

    // 2 w-positions per thread: reads float2/plane (coalesced), stores 64B/thread
    int id = blockIdx.x * 256 + threadIdx.x;   // 2048 rows x 1024 pairs
    int h  = id >> 10;
    int w0 = (id & 1023) << 1;
    const float* gp = x + h * WIN + w0;
    float2 v[16];
    #pragma unroll
    for (int ci = 0; ci < 16; ++ci) v[ci] = *(const float2*)(gp + ci * PLANE_IN);

    u32x4 lo0, hi0, lo1, hi1;
    #pragma unroll
    for (int p = 0; p < 4; ++p) {
        lo0[p] = pk2(v[2 * p].x,     v[2 * p + 1].x);
        hi0[p] = pk2(v[2 * p + 8].x, v[2 * p + 9].x);
        lo1[p] = pk2(v[2 * p].y,     v[2 * p + 1].y);
        hi1[p] = pk2(v[2 * p + 8].y, v[2 * p + 9].y);
    }
    int sw = (w0 & 4) ? 4 : 0;                 // chunk swap keyed on w&4 (same for w0+1)
    unsigned* op = xt + (h * WIN + w0) * 8;    // 8 u32 per position
    *(u32x4*)(op + sw)           = lo0;
    *(u32x4*)(op + (4 - sw))     = hi0;
    *(u32x4*)(op + 8 + sw)       = lo1;
    *(u32x4*)(op + 8 + (4 - sw)) = hi1;
}

// ---------------- pass 2: MFMA conv (512 threads / 8 waves) ----------------
__global__ __launch_bounds__(512, 8)
void conv3x3_mfma2(const unsigned* __restrict__ xt,
                   const unsigned* __restrict__ wfbuf,
                   float* __restrict__ out) {
    __shared__ unsigned lds[NCHUNK * 4];   // 36992 B, linear [row][col][ci-chunk]

    const int tid  = threadIdx.x;
    const int lane = tid & 63;
    const int wv   = tid >> 6;             // 0..7
    const int m    = lane & 15;
    const int g    = lane >> 4;

    int bid = blockIdx.x;
    int swz = (bid & 7) * 512 + (bid >> 3);    // XCD-chunked (4096 % 8 == 0)
    int h0 = (swz >> 6) * 32; if (h0 > HOUT - 32) h0 = HOUT - 32;  // 2014
    int w0 = (swz & 63) * 32;

    // ---- stage tile: 2312 chunks of 16B, linear LDS dest, per-lane gsrc ----
    {
        int base = wv * 64;
        #pragma unroll
        for (int pass = 0; pass < 4; ++pass) {
            int c   = pass * 512 + tid;
            int row = (c * 964) >> 16;          // c/68, exact for c<2312
            int sub = c - row * 68;
            int w   = w0 + (sub >> 1); if (w > WIN - 1) w = WIN - 1;
            const unsigned* src = xt + ((h0 + row) * WIN + w) * 8 + (sub & 1) * 4;
            __builtin_amdgcn_global_load_lds(
                (const __attribute__((address_space(1))) unsigned*)src,
                (__attribute__((address_space(3))) unsigned*)&lds[(pass * 512 + base) * 4],
                16, 0, 0);
        }
        if (tid < 264) {                        // tail: chunks 2048+tid .. 2311
            int c   = 2048 + tid;
            int row = (c * 964) >> 16;
            int sub = c - row * 68;
            int w   = w0 + (sub >> 1); if (w > WIN - 1) w = WIN - 1;
            const unsigned* src = xt + ((h0 + row) * WIN + w) * 8 + (sub & 1) * 4;
            __builtin_amdgcn_global_load_lds(
                (const __attribute__((address_space(1))) unsigned*)src,
                (__attribute__((address_space(3))) unsigned*)&lds[(2048 + base) * 4],
                16, 0, 0);
        }
    }

    // ---- weight fragments: 5 coalesced 16B loads (overlap staging latency) ----
    bf16x8 wf[5];
    #pragma unroll
    for (int i = 0; i < 5; ++i)
        wf[i] = *(const bf16x8*)(wfbuf + (i * 64 + lane) * 4);

    // ---- per-lane A-fragment LDS byte offsets ----
    int off[5];
    #pragma unroll
    for (int i = 0; i < 5; ++i) {
        int tap = 2 * i + (g >> 1);
        if (tap > 8) tap = 8;                   // dead K (weights are 0)
        int kh = tap / 3;
        int kw = tap - kh * 3;
        int col = m + kw;                       // wl enters via tile base (bit4-safe)
        int o = (kh * TC + col) * 32 + (g & 1) * 16;
        off[i] = o ^ ((col & 4) << 2);          // matches xt pre-swizzle
    }

    __syncthreads();

    const char* ldsb = (const char*)lds;

    #pragma unroll
    for (int hl4 = 0; hl4 < 4; ++hl4) {
        int hl = wv * 4 + hl4;                  // h always < HOUT (h0 <= 2014)
        int h  = h0 + hl;
        #pragma unroll
        for (int nh = 0; nh < 2; ++nh) {
            int wl = nh * 16;
            int tb = (hl * TC + wl) * 32;
            f32x4 acc = {0.f, 0.f, 0.f, 0.f};
            #pragma unroll
            for (int i = 0; i < 5; ++i) {
                bf16x8 a = *(const bf16x8*)(ldsb + (tb + off[i]));
                acc = __builtin_amdgcn_mfma_f32_16x16x32_bf16(a, wf[i], acc, 0, 0, 0);
            }
            // D: row = g*4+r = spatial, col = m = co  ->  float4 store
            int w = w0 + wl + g * 4;
            float* op = out + m * PLANE_OUT + h * WOUT + w;
            if (w + 3 < WOUT) {
                *(f32x4_u*)op = acc;
            } else {
                #pragma unroll
                for (int r = 0; r < 4; ++r)
                    if (w + r < WOUT) op[r] = acc[r];
            }
        }
    }
}

// ---------------- fallback (single-pass), used if ws too small ----------------
__global__ __launch_bounds__(256, 4)
void conv3x3_mfma(const float* __restrict__ x,
                  const float* __restrict__ k,
                  float* __restrict__ out) {
    __shared__ short lds[TR * TC * 16];
    const int tid  = threadIdx.x;
    const int lane = tid & 63;
    const int wv   = tid >> 6;
    const int m    = lane & 15;
    const int g    = lane >> 4;
    int bid = blockIdx.x;
    int swz = (bid & 7) * 512 + (bid >> 3);
    int h0 = (swz >> 6) * 32;
    int w0 = (swz & 63) * 32;
    for (int p = tid; p < TR * TC; p += 256) {
        int r = p / TC, c = p - r * TC;
        int hh = h0 + r; if (hh > HIN - 1) hh = HIN - 1;
        int ww = w0 + c; if (ww > WIN - 1) ww = WIN - 1;
        const float* gp = x + hh * WIN + ww;
        short t[16];
        #pragma unroll
        for (int ci = 0; ci < 16; ++ci) t[ci] = f2bf(gp[ci * PLANE_IN]);
        bf16x8 lo, hi;
        #pragma unroll
        for (int j = 0; j < 8; ++j) { lo[j] = t[j]; hi[j] = t[8 + j]; }
        int sw = (c >> 2) & 1;
        bf16x8* dst = (bf16x8*)&lds[p * 16];
        dst[sw] = lo; dst[1 - sw] = hi;
    }
    bf16x8 wf[5];
    #pragma unroll
    for (int i = 0; i < 5; ++i)
        #pragma unroll
        for (int j = 0; j < 8; ++j) {
            int kk = 32 * i + 8 * g + j;
            int tap = kk >> 4, ci = kk & 15;
            short v = 0;
            if (tap < 9) v = f2bf(k[(m * 16 + ci) * 9 + tap]);
            wf[i][j] = v;
        }
    int off[5];
    #pragma unroll
    for (int i = 0; i < 5; ++i) {
        int tap = 2 * i + (g >> 1);
        if (tap > 8) tap = 8;
        int kh = tap / 3, kw = tap - kh * 3;
        int col = m + kw;
        int o = (kh * TC + col) * 32 + (g & 1) * 16;
        off[i] = o ^ ((col & 4) << 2);
    }
    __syncthreads();
    const char* ldsb = (const char*)lds;
    const int coBase = g * 4;
    for (int hl8 = 0; hl8 < 8; ++hl8) {
        int hl = wv * 8 + hl8;
        int h = h0 + hl;
        bool hok = (h < HOUT);
        #pragma unroll
        for (int nh = 0; nh < 2; ++nh) {
            int wl = nh * 16;
            int tb = (hl * TC + wl) * 32;
            f32x4 acc = {0.f, 0.f, 0.f, 0.f};
            #pragma unroll
            for (int i = 0; i < 5; ++i) {
                bf16x8 b = *(const bf16x8*)(ldsb + (tb + off[i]));
                acc = __builtin_amdgcn_mfma_f32_16x16x32_bf16(wf[i], b, acc, 0, 0, 0);
            }
            int w = w0 + wl + m;
            if (hok && w < WOUT) {
                float* op = out + h * WOUT + w;
                #pragma unroll
                for (int r = 0; r < 4; ++r)
                    op[(coBase + r) * PLANE_OUT] = acc[r];
            }
        }
    }
}

extern "C" void kernel_launch(void* const* d_in, const int* in_sizes, int n_in,
                              void* d_out, int out_size, void* d_ws, size_t ws_size,
                              hipStream_t stream) {
    const float* x = (const float*)d_in[0];
    const float* k = (const float*)d_in[1];
    float* out = (float*)d_out;
    const size_t need = (XT_U32 + WF_U32) * 4;   // 128 MiB xt + 5 KiB wf
    if (ws_size >= need) {
        unsigned* xt = (unsigned*)d_ws;
        unsigned* wfbuf = xt + XT_U32;
        pack_bf16<<<dim3(8192), dim3(256), 0, stream>>>(x, k, xt, wfbuf);
        conv3x3_mfma2<<<dim3(4096), dim3(512), 0, stream>>>(xt, wfbuf, out);
    } else {
        conv3x3_mfma<<<dim3(4096), dim3(256), 0, stream>>>(x, k, out);
    }
}